// Round 6
// baseline (364.396 us; speedup 1.0000x reference)
//
#include <hip/hip_runtime.h>

#define BB 4
#define CC 256
#define DD 32
#define SS 4096

typedef __bf16 bf16;
typedef __bf16 bf16x8 __attribute__((ext_vector_type(8)));
typedef __bf16 bf16x4 __attribute__((ext_vector_type(4)));
typedef float f32x4 __attribute__((ext_vector_type(4)));
typedef unsigned int u32;
typedef unsigned short u16;

// workspace layout (bf16 elements):
//  q:  [2][BB][SS][DD]  off 0         size 1048576   (pos-major, 32 d inner)
//  k:  [2][BB][SS][DD]  off 1048576   size 1048576
//  v:  [2][BB][CC][SS]  off 2097152   size 8388608   (c-major, pos inner)
//  wb: [320][CC]        off 10485760  size 81920     (bf16 Wq|Wk|Wv stacked)
#define Q_OFF  0
#define K_OFF  1048576
#define V_OFF  2097152
#define WB_OFF 10485760

static __device__ __forceinline__ u32 pack2(float lo, float hi) {
    bf16 a = (bf16)lo, b = (bf16)hi;
    u16 ua = __builtin_bit_cast(u16, a), ub = __builtin_bit_cast(u16, b);
    return (u32)ua | ((u32)ub << 16);
}

// ------------------------------------------------- W fp32 -> bf16 [320][256]
__global__ __launch_bounds__(256) void convert_w_kernel(
    const float* __restrict__ Wq, const float* __restrict__ Wk,
    const float* __restrict__ Wv, bf16* __restrict__ wb)
{
    const int gid = blockIdx.x*256 + threadIdx.x;    // 40 blocks -> 10240
    const int idx = gid*8;                            // elem index, 8 per thread
    const int o = idx >> 8, cc = idx & 255;
    const float* row = (o < 32) ? (Wq + (size_t)o*CC)
                     : (o < 64) ? (Wk + (size_t)(o-32)*CC)
                                : (Wv + (size_t)(o-64)*CC);
    const float4 a = *(const float4*)(row + cc);
    const float4 c = *(const float4*)(row + cc + 4);
    bf16x8 pk;
    pk[0]=(bf16)a.x; pk[1]=(bf16)a.y; pk[2]=(bf16)a.z; pk[3]=(bf16)a.w;
    pk[4]=(bf16)c.x; pk[5]=(bf16)c.y; pk[6]=(bf16)c.z; pk[7]=(bf16)c.w;
    *(bf16x8*)(wb + idx) = pk;
}

// ------------------------------------------------- fused q,k,v projection (MFMA)
// C[pos][o] = sum_cc X[cc][pos] * W[o][cc] + bias[o];  o: 0-31 q, 32-63 k, 64-319 v
// M=pos (64/block), N=o (320), K=cc (256, 8 chunks of 32).
// bid: [2:0]=dirb (XCD locality), [8:3]=pos-tile.
__global__ __launch_bounds__(256, 2) void proj_all_kernel(
    const float* __restrict__ x, const float* __restrict__ y,
    const bf16* __restrict__ wb,
    const float* __restrict__ bq, const float* __restrict__ bk,
    const float* __restrict__ bv,
    bf16* __restrict__ qout, bf16* __restrict__ kout, bf16* __restrict__ vout)
{
    // xT: [64 pos][40 bf16] (stride 80 B, 16B-aligned rows; pair-packed b32 writes)
    __shared__ __align__(16) char smem[64*80];
    bf16* xT  = (bf16*)smem;
    u32*  xTw = (u32*)smem;

    const int t    = threadIdx.x;
    const int lane = t & 63;
    const int w    = t >> 6;
    const int ln   = lane & 15;
    const int quad = lane >> 4;

    const int bid  = blockIdx.x;
    const int dirb = bid & 7;
    const int src  = dirb >> 2;
    const int b    = dirb & 3;
    const int i0   = (bid >> 3) * 64;
    const float* in = src ? y : x;
    const float* xbase = in + (size_t)b*CC*SS + i0;

    // staging role: cc-pair cp, pos-quad pq
    const int cp = t >> 4;            // 0..15 -> cc {2cp, 2cp+1}
    const int pq = (t & 15) * 4;      // pos 0..60

    // per-wave o-range [80w, 80w+80): 5 n-blocks
    float bias[5];
    #pragma unroll
    for (int nbl = 0; nbl < 5; ++nbl) {
        const int o = 80*w + nbl*16 + ln;
        bias[nbl] = (o < 32) ? bq[o] : (o < 64) ? bk[o-32] : bv[o-64];
    }
    f32x4 acc[4][5];
    #pragma unroll
    for (int mb = 0; mb < 4; ++mb)
        #pragma unroll
        for (int nbl = 0; nbl < 5; ++nbl)
            acc[mb][nbl] = (f32x4){bias[nbl], bias[nbl], bias[nbl], bias[nbl]};

    const bf16* wrow = wb + (size_t)(80*w + ln)*CC + quad*8;
    bf16x8 bf[5];
    #pragma unroll
    for (int nbl = 0; nbl < 5; ++nbl)
        bf[nbl] = *(const bf16x8*)(wrow + (size_t)nbl*16*CC);

    for (int cc0 = 0; cc0 < CC; cc0 += 32) {
        // stage X chunk [32 cc][64 pos] -> xT[pos][cc] bf16 (pair-packed b32)
        {
            const float* r0 = xbase + (size_t)(cc0 + 2*cp)*SS + pq;
            const float4 a0 = *(const float4*)r0;
            const float4 a1 = *(const float4*)(r0 + SS);
            xTw[(pq+0)*20 + cp] = pack2(a0.x, a1.x);
            xTw[(pq+1)*20 + cp] = pack2(a0.y, a1.y);
            xTw[(pq+2)*20 + cp] = pack2(a0.z, a1.z);
            xTw[(pq+3)*20 + cp] = pack2(a0.w, a1.w);
        }
        __syncthreads();
        bf16x8 af[4];
        #pragma unroll
        for (int mb = 0; mb < 4; ++mb)
            af[mb] = *(const bf16x8*)(xT + (mb*16 + ln)*40 + quad*8);
        #pragma unroll
        for (int mb = 0; mb < 4; ++mb)
            #pragma unroll
            for (int nbl = 0; nbl < 5; ++nbl)
                acc[mb][nbl] = __builtin_amdgcn_mfma_f32_16x16x32_bf16(
                                   af[mb], bf[nbl], acc[mb][nbl], 0, 0, 0);
        // prefetch next W chunk (wrap keeps last-iter loads in-bounds)
        const int ccn = (cc0 + 32) & 255;
        #pragma unroll
        for (int nbl = 0; nbl < 5; ++nbl)
            bf[nbl] = *(const bf16x8*)(wrow + (size_t)nbl*16*CC + ccn);
        __syncthreads();
    }

    // stores: D col=ln -> o, row=quad*4+r -> pos
    bf16* qo = qout + (size_t)(src*BB + b)*SS*DD;
    bf16* ko = kout + (size_t)(src*BB + b)*SS*DD;
    bf16* vo = vout + (size_t)(src*BB + b)*CC*SS;
    #pragma unroll
    for (int nbl = 0; nbl < 5; ++nbl) {
        const int o = 80*w + nbl*16 + ln;
        if (o < 32) {
            #pragma unroll
            for (int mb = 0; mb < 4; ++mb)
                #pragma unroll
                for (int r = 0; r < 4; ++r)
                    qo[(size_t)(i0 + mb*16 + quad*4 + r)*DD + o] = (bf16)acc[mb][nbl][r];
        } else if (o < 64) {
            #pragma unroll
            for (int mb = 0; mb < 4; ++mb)
                #pragma unroll
                for (int r = 0; r < 4; ++r)
                    ko[(size_t)(i0 + mb*16 + quad*4 + r)*DD + (o-32)] = (bf16)acc[mb][nbl][r];
        } else {
            const int c = o - 64;
            #pragma unroll
            for (int mb = 0; mb < 4; ++mb) {
                bf16x4 pk;
                #pragma unroll
                for (int r = 0; r < 4; ++r) pk[r] = (bf16)acc[mb][nbl][r];
                *(bf16x4*)(vo + (size_t)c*SS + i0 + mb*16 + quad*4) = pk;
            }
        }
    }
}

// ------------------------------------------------- attention
// Block: 64 queries x 128 channels (cq half). 4 waves:
//   qp = w&1 -> q rows [32qp, 32qp+32); kr = w>>1 -> key sub-range / c half.
// S: wave computes its 32 q x its 32 keys (no redundancy). P via LDS
// (stride-72 rows, double-buffered, 1 barrier/chunk). K/V/Q direct global,
// prefetched. Fixed-max softmax. bid: [2:0]=dirb (XCD), [3]=cq, [9:4]=qt.
#define SM_M 16.0f

__global__ __launch_bounds__(256, 4) void attn_kernel(
    const bf16* __restrict__ qg, const bf16* __restrict__ kg,
    const bf16* __restrict__ vg, float* __restrict__ out)
{
    __shared__ __align__(16) char smem[2*4608*2 + 512];
    bf16*  p_s  = (bf16*)smem;             // [2][64][72]
    float* l2_s = (float*)(smem + 18432);  // [2][64]

    const int t    = threadIdx.x;
    const int lane = t & 63;
    const int w    = t >> 6;
    const int ln   = lane & 15;
    const int quad = lane >> 4;
    const int qp   = w & 1;
    const int kr   = w >> 1;

    const int bid  = blockIdx.x;
    const int dirb = bid & 7;
    const int dir  = dirb >> 2;
    const int b    = dirb & 3;
    const int cq   = (bid >> 3) & 1;
    const int qt   = bid >> 4;
    const int i0   = qt*64;
    const int c0   = cq*128;

    const bf16* q = qg + ((size_t)dir*BB + b)*SS*DD + (size_t)i0*DD;
    const bf16* k = kg + ((size_t)(1-dir)*BB + b)*SS*DD;
    const bf16* v = vg + ((size_t)(1-dir)*BB + b)*CC*SS;
    float* op = out + ((size_t)dir*BB + b)*CC*SS;

    // Q A-frags for this wave's two 16-q blocks
    bf16x8 a_q[2];
    #pragma unroll
    for (int qb2 = 0; qb2 < 2; ++qb2)
        a_q[qb2] = *(const bf16x8*)(q + (size_t)((2*qp + qb2)*16 + ln)*DD + quad*8);

    // K: this wave's 32-key sub-range; V: this wave's 64-c range
    const bf16* kptr = k + (size_t)(kr*32 + ln)*DD + quad*8;   // + (j0 + knb2*16)*DD
    const bf16* vptr[4];
    #pragma unroll
    for (int cb = 0; cb < 4; ++cb)
        vptr[cb] = v + (size_t)(c0 + kr*64 + cb*16 + ln)*SS + quad*8;  // + j0 + ks*32

    f32x4 o[2][4];
    #pragma unroll
    for (int qb2 = 0; qb2 < 2; ++qb2)
        #pragma unroll
        for (int cb = 0; cb < 4; ++cb) o[qb2][cb] = (f32x4){0.f,0.f,0.f,0.f};
    float lpart[2][4];
    #pragma unroll
    for (int qb2 = 0; qb2 < 2; ++qb2)
        #pragma unroll
        for (int r = 0; r < 4; ++r) lpart[qb2][r] = 0.f;

    // prefetch chunk 0
    bf16x8 kf[2], vf[2][4];
    #pragma unroll
    for (int knb2 = 0; knb2 < 2; ++knb2)
        kf[knb2] = *(const bf16x8*)(kptr + (size_t)(knb2*16)*DD);
    #pragma unroll
    for (int ks = 0; ks < 2; ++ks)
        #pragma unroll
        for (int cb = 0; cb < 4; ++cb)
            vf[ks][cb] = *(const bf16x8*)(vptr[cb] + ks*32);

    for (int j0 = 0; j0 < SS; j0 += 64) {
        // S: 2 qb x 2 key-nb (this wave's quarter of the 64x64 tile)
        f32x4 s[2][2];
        #pragma unroll
        for (int qb2 = 0; qb2 < 2; ++qb2)
            #pragma unroll
            for (int knb2 = 0; knb2 < 2; ++knb2)
                s[qb2][knb2] = __builtin_amdgcn_mfma_f32_16x16x32_bf16(
                    a_q[qb2], kf[knb2], (f32x4){0.f,0.f,0.f,0.f}, 0, 0, 0);

        const int jn = (j0 + 64) & (SS - 1);
        #pragma unroll
        for (int knb2 = 0; knb2 < 2; ++knb2)
            kf[knb2] = *(const bf16x8*)(kptr + (size_t)(jn + knb2*16)*DD);

        // fixed-max softmax; write P strip (rows: own q's, cols: own keys)
        bf16* pb = p_s + ((j0 >> 6) & 1)*4608;
        #pragma unroll
        for (int qb2 = 0; qb2 < 2; ++qb2)
            #pragma unroll
            for (int knb2 = 0; knb2 < 2; ++knb2) {
                const int col = kr*32 + knb2*16 + ln;
                #pragma unroll
                for (int r = 0; r < 4; ++r) {
                    const float e = __expf(fminf(s[qb2][knb2][r] - SM_M, 60.0f));
                    lpart[qb2][r] += e;
                    pb[((2*qp + qb2)*16 + quad*4 + r)*72 + col] = (bf16)e;
                }
            }
        __syncthreads();   // P complete (all waves); also sequences buffer reuse

        // O += P V  (own q rows x own c range; P cols span both key halves)
        #pragma unroll
        for (int ks = 0; ks < 2; ++ks) {
            bf16x8 ap[2];
            #pragma unroll
            for (int qb2 = 0; qb2 < 2; ++qb2)
                ap[qb2] = *(const bf16x8*)(pb + ((2*qp + qb2)*16 + ln)*72 + ks*32 + quad*8);
            #pragma unroll
            for (int qb2 = 0; qb2 < 2; ++qb2)
                #pragma unroll
                for (int cb = 0; cb < 4; ++cb)
                    o[qb2][cb] = __builtin_amdgcn_mfma_f32_16x16x32_bf16(
                                     ap[qb2], vf[ks][cb], o[qb2][cb], 0, 0, 0);
        }
        // prefetch next V
        #pragma unroll
        for (int ks = 0; ks < 2; ++ks)
            #pragma unroll
            for (int cb = 0; cb < 4; ++cb)
                vf[ks][cb] = *(const bf16x8*)(vptr[cb] + jn + ks*32);
    }

    // l: butterfly over 16-lane key-cols, combine the two key-halves via LDS
    #pragma unroll
    for (int qb2 = 0; qb2 < 2; ++qb2)
        #pragma unroll
        for (int r = 0; r < 4; ++r) {
            float lr = lpart[qb2][r];
            lr += __shfl_xor(lr, 1);
            lr += __shfl_xor(lr, 2);
            lr += __shfl_xor(lr, 4);
            lr += __shfl_xor(lr, 8);
            lpart[qb2][r] = lr;
        }
    if (ln == 0) {
        #pragma unroll
        for (int qb2 = 0; qb2 < 2; ++qb2)
            #pragma unroll
            for (int r = 0; r < 4; ++r)
                l2_s[kr*64 + (2*qp + qb2)*16 + quad*4 + r] = lpart[qb2][r];
    }
    __syncthreads();

    // epilogue: per-wave stores; one wave-inst writes 16 full 64B sectors
    #pragma unroll
    for (int qb2 = 0; qb2 < 2; ++qb2) {
        float rinv[4];
        #pragma unroll
        for (int r = 0; r < 4; ++r) {
            const int qi = (2*qp + qb2)*16 + quad*4 + r;
            rinv[r] = 1.0f / (l2_s[qi] + l2_s[64 + qi]);
        }
        #pragma unroll
        for (int cb = 0; cb < 4; ++cb) {
            const int c = c0 + kr*64 + cb*16 + ln;
            float4 val = make_float4(o[qb2][cb][0]*rinv[0], o[qb2][cb][1]*rinv[1],
                                     o[qb2][cb][2]*rinv[2], o[qb2][cb][3]*rinv[3]);
            *(float4*)(op + (size_t)c*SS + i0 + (2*qp + qb2)*16 + quad*4) = val;
        }
    }
}

// ------------------------------------------------- launch
extern "C" void kernel_launch(void* const* d_in, const int* in_sizes, int n_in,
                              void* d_out, int out_size, void* d_ws, size_t ws_size,
                              hipStream_t stream)
{
    const float* x  = (const float*)d_in[0];
    const float* y  = (const float*)d_in[1];
    const float* Wq = (const float*)d_in[2];
    const float* bq = (const float*)d_in[3];
    const float* Wk = (const float*)d_in[4];
    const float* bk = (const float*)d_in[5];
    const float* Wv = (const float*)d_in[6];
    const float* bv = (const float*)d_in[7];
    float* out = (float*)d_out;
    bf16* ws   = (bf16*)d_ws;

    bf16* qw = ws + Q_OFF;
    bf16* kw = ws + K_OFF;
    bf16* vw = ws + V_OFF;
    bf16* wb = ws + WB_OFF;

    convert_w_kernel<<<40,   256, 0, stream>>>(Wq, Wk, Wv, wb);
    proj_all_kernel <<<512,  256, 0, stream>>>(x, y, wb, bq, bk, bv, qw, kw, vw);
    attn_kernel     <<<1024, 256, 0, stream>>>(qw, kw, vw, out);
}

// Round 7
// 253.329 us; speedup vs baseline: 1.4384x; 1.4384x over previous
//
#include <hip/hip_runtime.h>

#define BB 4
#define CC 256
#define DD 32
#define SS 4096

typedef __bf16 bf16;
typedef __bf16 bf16x8 __attribute__((ext_vector_type(8)));
typedef __bf16 bf16x4 __attribute__((ext_vector_type(4)));
typedef float f32x4 __attribute__((ext_vector_type(4)));
typedef unsigned int u32;
typedef unsigned short u16;

// workspace layout (bf16 elements):
//  q:  [2][BB][SS][DD]  off 0         (pos-major, 32 d inner)
//  k:  [2][BB][SS][DD]  off 1048576
//  v:  [2][BB][CC][SS]  off 2097152   (c-major, pos inner)
//  wb: [320][CC]        off 10485760  (bf16 Wq|Wk|Wv stacked)
#define Q_OFF  0
#define K_OFF  1048576
#define V_OFF  2097152
#define WB_OFF 10485760

static __device__ __forceinline__ u32 pack2(float lo, float hi) {
    bf16 a = (bf16)lo, b = (bf16)hi;
    u16 ua = __builtin_bit_cast(u16, a), ub = __builtin_bit_cast(u16, b);
    return (u32)ua | ((u32)ub << 16);
}

// ------------------------------------------------- W fp32 -> bf16 [320][256]
__global__ __launch_bounds__(256) void convert_w_kernel(
    const float* __restrict__ Wq, const float* __restrict__ Wk,
    const float* __restrict__ Wv, bf16* __restrict__ wb)
{
    const int gid = blockIdx.x*256 + threadIdx.x;    // 40 blocks -> 10240
    const int idx = gid*8;
    const int o = idx >> 8, cc = idx & 255;
    const float* row = (o < 32) ? (Wq + (size_t)o*CC)
                     : (o < 64) ? (Wk + (size_t)(o-32)*CC)
                                : (Wv + (size_t)(o-64)*CC);
    const float4 a = *(const float4*)(row + cc);
    const float4 c = *(const float4*)(row + cc + 4);
    bf16x8 pk;
    pk[0]=(bf16)a.x; pk[1]=(bf16)a.y; pk[2]=(bf16)a.z; pk[3]=(bf16)a.w;
    pk[4]=(bf16)c.x; pk[5]=(bf16)c.y; pk[6]=(bf16)c.z; pk[7]=(bf16)c.w;
    *(bf16x8*)(wb + idx) = pk;
}

// ------------------------------------------------- fused q,k,v projection (MFMA)
// C[pos][o] = sum_cc X[cc][pos]*W[o][cc] + bias;  o: 0-31 q, 32-63 k, 64-319 v
// Double-buffered xT + register X-prefetch: 1 barrier/chunk, loads in flight.
__global__ __launch_bounds__(256, 2) void proj_all_kernel(
    const float* __restrict__ x, const float* __restrict__ y,
    const bf16* __restrict__ wb,
    const float* __restrict__ bq, const float* __restrict__ bk,
    const float* __restrict__ bv,
    bf16* __restrict__ qout, bf16* __restrict__ kout, bf16* __restrict__ vout)
{
    // xT: [2][64 pos][40 bf16] (row 80 B, 16B-aligned)
    __shared__ __align__(16) char smem[2*5120];
    bf16* xT  = (bf16*)smem;
    u32*  xTw = (u32*)smem;

    const int t    = threadIdx.x;
    const int lane = t & 63;
    const int w    = t >> 6;
    const int ln   = lane & 15;
    const int quad = lane >> 4;

    const int bid  = blockIdx.x;
    const int dirb = bid & 7;
    const int src  = dirb >> 2;
    const int b    = dirb & 3;
    const int i0   = (bid >> 3) * 64;
    const float* in = src ? y : x;
    const float* xbase = in + (size_t)b*CC*SS + i0;

    const int cp = t >> 4;            // cc-pair 0..15 -> cc {2cp, 2cp+1}
    const int pq = (t & 15) * 4;      // pos 0..60

    float bias[5];
    #pragma unroll
    for (int nbl = 0; nbl < 5; ++nbl) {
        const int o = 80*w + nbl*16 + ln;
        bias[nbl] = (o < 32) ? bq[o] : (o < 64) ? bk[o-32] : bv[o-64];
    }
    f32x4 acc[4][5];
    #pragma unroll
    for (int mb = 0; mb < 4; ++mb)
        #pragma unroll
        for (int nbl = 0; nbl < 5; ++nbl)
            acc[mb][nbl] = (f32x4){bias[nbl], bias[nbl], bias[nbl], bias[nbl]};

    const bf16* wrow = wb + (size_t)(80*w + ln)*CC + quad*8;
    bf16x8 bf[5];
    #pragma unroll
    for (int nbl = 0; nbl < 5; ++nbl)
        bf[nbl] = *(const bf16x8*)(wrow + (size_t)nbl*16*CC);

    // stage chunk 0 into buf0
    {
        const float* r0 = xbase + (size_t)(2*cp)*SS + pq;
        const float4 a0 = *(const float4*)r0;
        const float4 a1 = *(const float4*)(r0 + SS);
        xTw[(pq+0)*20 + cp] = pack2(a0.x, a1.x);
        xTw[(pq+1)*20 + cp] = pack2(a0.y, a1.y);
        xTw[(pq+2)*20 + cp] = pack2(a0.z, a1.z);
        xTw[(pq+3)*20 + cp] = pack2(a0.w, a1.w);
    }
    // prefetch chunk 1 into regs
    float4 a0, a1;
    {
        const float* r1 = xbase + (size_t)(32 + 2*cp)*SS + pq;
        a0 = *(const float4*)r1;
        a1 = *(const float4*)(r1 + SS);
    }
    __syncthreads();

    for (int n = 0; n < 8; ++n) {
        bf16x8 af[4];
        #pragma unroll
        for (int mb = 0; mb < 4; ++mb)
            af[mb] = *(const bf16x8*)(xT + (n&1)*2560 + (mb*16 + ln)*40 + quad*8);
        // write prefetched chunk n+1 into other buffer
        if (n < 7) {
            u32* dst = xTw + ((n+1)&1)*1280;
            dst[(pq+0)*20 + cp] = pack2(a0.x, a1.x);
            dst[(pq+1)*20 + cp] = pack2(a0.y, a1.y);
            dst[(pq+2)*20 + cp] = pack2(a0.z, a1.z);
            dst[(pq+3)*20 + cp] = pack2(a0.w, a1.w);
        }
        // prefetch chunk n+2 regs (wrap keeps loads in-bounds; redundant at tail)
        {
            const int cc2 = ((n+2)*32) & 255;
            const float* r2 = xbase + (size_t)(cc2 + 2*cp)*SS + pq;
            a0 = *(const float4*)r2;
            a1 = *(const float4*)(r2 + SS);
        }
        #pragma unroll
        for (int mb = 0; mb < 4; ++mb)
            #pragma unroll
            for (int nbl = 0; nbl < 5; ++nbl)
                acc[mb][nbl] = __builtin_amdgcn_mfma_f32_16x16x32_bf16(
                                   af[mb], bf[nbl], acc[mb][nbl], 0, 0, 0);
        // prefetch next W chunk
        const int ccn = ((n+1)*32) & 255;
        #pragma unroll
        for (int nbl = 0; nbl < 5; ++nbl)
            bf[nbl] = *(const bf16x8*)(wrow + (size_t)nbl*16*CC + ccn);
        __syncthreads();
    }

    bf16* qo = qout + (size_t)(src*BB + b)*SS*DD;
    bf16* ko = kout + (size_t)(src*BB + b)*SS*DD;
    bf16* vo = vout + (size_t)(src*BB + b)*CC*SS;
    #pragma unroll
    for (int nbl = 0; nbl < 5; ++nbl) {
        const int o = 80*w + nbl*16 + ln;
        if (o < 32) {
            #pragma unroll
            for (int mb = 0; mb < 4; ++mb)
                #pragma unroll
                for (int r = 0; r < 4; ++r)
                    qo[(size_t)(i0 + mb*16 + quad*4 + r)*DD + o] = (bf16)acc[mb][nbl][r];
        } else if (o < 64) {
            #pragma unroll
            for (int mb = 0; mb < 4; ++mb)
                #pragma unroll
                for (int r = 0; r < 4; ++r)
                    ko[(size_t)(i0 + mb*16 + quad*4 + r)*DD + (o-32)] = (bf16)acc[mb][nbl][r];
        } else {
            const int c = o - 64;
            #pragma unroll
            for (int mb = 0; mb < 4; ++mb) {
                bf16x4 pk;
                #pragma unroll
                for (int r = 0; r < 4; ++r) pk[r] = (bf16)acc[mb][nbl][r];
                *(bf16x4*)(vo + (size_t)c*SS + i0 + mb*16 + quad*4) = pk;
            }
        }
    }
}

// ------------------------------------------------- attention (pipelined, S^T)
// Block: 64 queries x 256 c; wave w: S^T for queries [16w,16w+16), PV c-range
// [64w, 64w+64). S^T = mfma(K_frag, Q_frag): lane holds (key=quad*4+r, q=ln)
// -> P write = 4 x b64 vector stores (conflict-free @ stride 72). P double-
// buffered; S^T(n+1)+softmax(n+1) overlap PV(n); 1 barrier/chunk.
#define SM_M 16.0f

__global__ __launch_bounds__(256, 2) void attn_kernel(
    const bf16* __restrict__ qg, const bf16* __restrict__ kg,
    const bf16* __restrict__ vg, float* __restrict__ out)
{
    __shared__ __align__(16) char smem[18688];
    bf16*  p_s = (bf16*)smem;               // [2][64][72]
    float* l_s = (float*)(smem + 18432);    // [64]

    const int t    = threadIdx.x;
    const int lane = t & 63;
    const int w    = t >> 6;
    const int ln   = lane & 15;
    const int quad = lane >> 4;

    const int bid  = blockIdx.x;
    const int dirb = bid & 7;
    const int dir  = dirb >> 2;
    const int b    = dirb & 3;
    const int i0   = (bid >> 3) * 64;

    const bf16* q = qg + ((size_t)dir*BB + b)*SS*DD + (size_t)i0*DD;
    const bf16* k = kg + ((size_t)(1-dir)*BB + b)*SS*DD;
    const bf16* v = vg + ((size_t)(1-dir)*BB + b)*CC*SS;
    float* op = out + ((size_t)dir*BB + b)*CC*SS;

    // Q as B-frag: B[n=q(ln)][k=d(quad*8+)]  (wave's 16 queries)
    const bf16x8 b_q = *(const bf16x8*)(q + (size_t)(w*16 + ln)*DD + quad*8);
    // K as A-frag base: A[m=key(ln)][k=d(quad*8+)]
    const bf16* kbase = k + (size_t)ln*DD + quad*8;
    const bf16* vptr[4];
    #pragma unroll
    for (int cb = 0; cb < 4; ++cb)
        vptr[cb] = v + (size_t)(w*64 + cb*16 + ln)*SS + quad*8;

    f32x4 o[4][4];
    #pragma unroll
    for (int qb = 0; qb < 4; ++qb)
        #pragma unroll
        for (int cb = 0; cb < 4; ++cb) o[qb][cb] = (f32x4){0.f,0.f,0.f,0.f};
    float lp = 0.f;

    bf16x8 kf[4], vf[2][4];
    #pragma unroll
    for (int nb = 0; nb < 4; ++nb)
        kf[nb] = *(const bf16x8*)(kbase + (size_t)(nb*16)*DD);
    #pragma unroll
    for (int ks = 0; ks < 2; ++ks)
        #pragma unroll
        for (int cb = 0; cb < 4; ++cb)
            vf[ks][cb] = *(const bf16x8*)(vptr[cb] + ks*32);

    // prologue: S^T(0) + softmax(0) -> buf0
    {
        f32x4 s[4];
        #pragma unroll
        for (int nb = 0; nb < 4; ++nb)
            s[nb] = __builtin_amdgcn_mfma_f32_16x16x32_bf16(
                        kf[nb], b_q, (f32x4){0.f,0.f,0.f,0.f}, 0, 0, 0);
        #pragma unroll
        for (int nb = 0; nb < 4; ++nb)
            kf[nb] = *(const bf16x8*)(kbase + (size_t)(64 + nb*16)*DD);
        #pragma unroll
        for (int nb = 0; nb < 4; ++nb) {
            bf16x4 pk;
            #pragma unroll
            for (int r = 0; r < 4; ++r) {
                const float e = __expf(fminf(s[nb][r] - SM_M, 60.0f));
                lp += e;
                pk[r] = (bf16)e;
            }
            *(bf16x4*)(p_s + (w*16 + ln)*72 + nb*16 + quad*4) = pk;
        }
    }

    for (int n = 0; n < 64; ++n) {
        __syncthreads();   // P(n) visible; buf((n+1)&1) free (PV(n-1) done)
        const bf16* pr = p_s + (n & 1)*4608;
        bf16* pw = p_s + ((n + 1) & 1)*4608;

        f32x4 s[4];
        if (n < 63) {
            // S^T(n+1): independent of P(n) -> co-issues with PV(n)
            #pragma unroll
            for (int nb = 0; nb < 4; ++nb)
                s[nb] = __builtin_amdgcn_mfma_f32_16x16x32_bf16(
                            kf[nb], b_q, (f32x4){0.f,0.f,0.f,0.f}, 0, 0, 0);
            const int j2 = ((n + 2) << 6) & (SS - 1);
            #pragma unroll
            for (int nb = 0; nb < 4; ++nb)
                kf[nb] = *(const bf16x8*)(kbase + (size_t)(j2 + nb*16)*DD);
        }

        // PV(n)
        #pragma unroll
        for (int ks = 0; ks < 2; ++ks) {
            bf16x8 ap[4];
            #pragma unroll
            for (int qb = 0; qb < 4; ++qb)
                ap[qb] = *(const bf16x8*)(pr + (qb*16 + ln)*72 + ks*32 + quad*8);
            #pragma unroll
            for (int qb = 0; qb < 4; ++qb)
                #pragma unroll
                for (int cb = 0; cb < 4; ++cb)
                    o[qb][cb] = __builtin_amdgcn_mfma_f32_16x16x32_bf16(
                                    ap[qb], vf[ks][cb], o[qb][cb], 0, 0, 0);
        }
        // V(n+1)
        const int j1 = ((n + 1) << 6) & (SS - 1);
        #pragma unroll
        for (int ks = 0; ks < 2; ++ks)
            #pragma unroll
            for (int cb = 0; cb < 4; ++cb)
                vf[ks][cb] = *(const bf16x8*)(vptr[cb] + j1 + ks*32);

        if (n < 63) {
            // softmax(n+1) -> pw (4 b64 stores; S-mfma results long ready)
            #pragma unroll
            for (int nb = 0; nb < 4; ++nb) {
                bf16x4 pk;
                #pragma unroll
                for (int r = 0; r < 4; ++r) {
                    const float e = __expf(fminf(s[nb][r] - SM_M, 60.0f));
                    lp += e;
                    pk[r] = (bf16)e;
                }
                *(bf16x4*)(pw + (w*16 + ln)*72 + nb*16 + quad*4) = pk;
            }
        }
    }

    // l: lane covers keys {*, nb*16+quad*4+r} for query w*16+ln -> reduce quads
    lp += __shfl_xor(lp, 16);
    lp += __shfl_xor(lp, 32);
    if (lane < 16) l_s[w*16 + ln] = lp;
    __syncthreads();

    // epilogue: normalize + direct coalesced stores
    #pragma unroll
    for (int qb = 0; qb < 4; ++qb) {
        const f32x4 lq = *(const f32x4*)(l_s + qb*16 + quad*4);
        const float ri0 = 1.0f/lq[0], ri1 = 1.0f/lq[1], ri2 = 1.0f/lq[2], ri3 = 1.0f/lq[3];
        #pragma unroll
        for (int cb = 0; cb < 4; ++cb) {
            const int c = w*64 + cb*16 + ln;
            float4 val = make_float4(o[qb][cb][0]*ri0, o[qb][cb][1]*ri1,
                                     o[qb][cb][2]*ri2, o[qb][cb][3]*ri3);
            *(float4*)(op + (size_t)c*SS + i0 + qb*16 + quad*4) = val;
        }
    }
}

// ------------------------------------------------- launch
extern "C" void kernel_launch(void* const* d_in, const int* in_sizes, int n_in,
                              void* d_out, int out_size, void* d_ws, size_t ws_size,
                              hipStream_t stream)
{
    const float* x  = (const float*)d_in[0];
    const float* y  = (const float*)d_in[1];
    const float* Wq = (const float*)d_in[2];
    const float* bq = (const float*)d_in[3];
    const float* Wk = (const float*)d_in[4];
    const float* bk = (const float*)d_in[5];
    const float* Wv = (const float*)d_in[6];
    const float* bv = (const float*)d_in[7];
    float* out = (float*)d_out;
    bf16* ws   = (bf16*)d_ws;

    bf16* qw = ws + Q_OFF;
    bf16* kw = ws + K_OFF;
    bf16* vw = ws + V_OFF;
    bf16* wb = ws + WB_OFF;

    convert_w_kernel<<<40,  256, 0, stream>>>(Wq, Wk, Wv, wb);
    proj_all_kernel <<<512, 256, 0, stream>>>(x, y, wb, bq, bk, bv, qw, kw, vw);
    attn_kernel     <<<512, 256, 0, stream>>>(qw, kw, vw, out);
}